// Round 14
// baseline (523.601 us; speedup 1.0000x reference)
//
#include <hip/hip_runtime.h>
#include <hip/hip_bf16.h>
#include <stdint.h>

#define NTOK 131072
#define NE 16

typedef __attribute__((ext_vector_type(8))) short short8;
typedef __attribute__((ext_vector_type(4))) float f32x4;

#define AS1 __attribute__((address_space(1)))
#define AS3 __attribute__((address_space(3)))

__device__ __forceinline__ ushort f2bf(float f) {
    __hip_bfloat16 h = __float2bfloat16(f);
    return *reinterpret_cast<ushort*>(&h);
}

// ---- ws layout (bytes) ----
// 0        : WeT bf16 [16][512n][512k]          8,388,608
// 8388608  : logits f32 [NTOK][16]              8,388,608
// 16777216 : listA int [NTOK]   (first 2KB doubles as gate partials before scatter)
// 17301504 : wA f32 [NTOK]
// 17825792 : listB int [NTOK]
// 18350080 : wB f32 [NTOK]
// 18874368 : eP int [NTOK]
// 19398656 : wP float2 [NTOK]
// 20447232 : ctrl int[144]
// 20451328 : blockHist int[128][32]             16,384
// 20480000 : xbf bf16 [NTOK][512]              134,217,728   (only if ws_size permits)

__global__ void k_init(int* ctrl) {
    int tid = threadIdx.x;
    if (tid < 144) ctrl[tid] = 0;
}

// ---- transpose+convert We[e][k][n] f32 -> WeT[e][n][k] bf16 ----
__global__ __launch_bounds__(256) void k_wet(const float* __restrict__ We, ushort* __restrict__ WeT) {
    __shared__ float t[64][65];
    int e = blockIdx.z, k0 = blockIdx.x * 64, n0 = blockIdx.y * 64;
    int tid = threadIdx.x;
    const float* src = We + ((size_t)e * 512 + k0) * 512 + n0;
    #pragma unroll
    for (int i = 0; i < 16; i++) {
        int idx = i * 256 + tid;
        int r = idx >> 6, c = idx & 63;
        t[r][c] = src[(size_t)r * 512 + c];
    }
    __syncthreads();
    ushort* dst = WeT + ((size_t)e * 512 + n0) * 512 + k0;
    #pragma unroll
    for (int i = 0; i < 16; i++) {
        int idx = i * 256 + tid;
        int rn = idx >> 6, ck = idx & 63;
        dst[(size_t)rn * 512 + ck] = f2bf(t[ck][rn]);
    }
}

// ---- gating: logits = x@Wg + bg (f32, LDS-staged coalesced); partial of sum||logits||; bf16 x ----
__global__ __launch_bounds__(256) void k_gate(const float* __restrict__ x, const float* __restrict__ Wg,
                                              const float* __restrict__ bg, float* __restrict__ logits,
                                              float* __restrict__ partials, ushort* __restrict__ xbf) {
    __shared__ float WgL[512 * 16];     // 32 KB
    __shared__ float xs[256][33];       // 33.8 KB
    __shared__ float wsum[4];
    const int tid = threadIdx.x;
    #pragma unroll
    for (int i = 0; i < 32; i++) WgL[i * 256 + tid] = Wg[i * 256 + tid];
    const size_t tokBase = (size_t)blockIdx.x * 256;
    float acc[16];
    #pragma unroll
    for (int e = 0; e < 16; e++) acc[e] = 0.f;

    for (int kc = 0; kc < 16; kc++) {
        __syncthreads();
        #pragma unroll
        for (int i = 0; i < 8; i++) {
            int idx = (i << 8) + tid;
            int rr = idx >> 3, cq = (idx & 7) << 2;
            const float4 v = *(const float4*)&x[(tokBase + rr) * 512 + (kc << 5) + cq];
            xs[rr][cq] = v.x; xs[rr][cq + 1] = v.y; xs[rr][cq + 2] = v.z; xs[rr][cq + 3] = v.w;
            if (xbf) {
                ushort4 uw;
                uw.x = f2bf(v.x); uw.y = f2bf(v.y); uw.z = f2bf(v.z); uw.w = f2bf(v.w);
                *(ushort4*)&xbf[(tokBase + rr) * 512 + (kc << 5) + cq] = uw;
            }
        }
        __syncthreads();
        #pragma unroll
        for (int j = 0; j < 32; j++) {
            float xv = xs[tid][j];
            const float* wr = &WgL[((kc << 5) + j) << 4];
            #pragma unroll
            for (int e = 0; e < 16; e++) acc[e] = fmaf(xv, wr[e], acc[e]);
        }
    }

    float lg[16];
    float ss = 0.f;
    #pragma unroll
    for (int e = 0; e < 16; e++) {
        float v = acc[e] + bg[e];
        lg[e] = v;
        ss += v * v;
    }
    float gx = sqrtf(ss);
    float r = gx;
    #pragma unroll
    for (int off = 32; off >= 1; off >>= 1) r += __shfl_down(r, off);
    if ((tid & 63) == 0) wsum[tid >> 6] = r;
    __syncthreads();
    if (tid == 0) partials[blockIdx.x] = wsum[0] + wsum[1] + wsum[2] + wsum[3];
    float4* lo = (float4*)(logits + (tokBase + tid) * 16);
    lo[0] = make_float4(lg[0], lg[1], lg[2], lg[3]);
    lo[1] = make_float4(lg[4], lg[5], lg[6], lg[7]);
    lo[2] = make_float4(lg[8], lg[9], lg[10], lg[11]);
    lo[3] = make_float4(lg[12], lg[13], lg[14], lg[15]);
}

// ---- reduce 512 gate partials -> sumGx ----
__global__ void k_redsum(const float* __restrict__ partials, float* __restrict__ sumGx) {
    int tid = threadIdx.x;  // 64
    float s = 0.f;
    #pragma unroll
    for (int i = 0; i < 8; i++) s += partials[tid + i * 64];
    #pragma unroll
    for (int off = 32; off >= 1; off >>= 1) s += __shfl_down(s, off);
    if (tid == 0) *sumGx = s;
}

// ---- GRN + softmax + top2 + per-expert counts + per-block histograms ----
__global__ __launch_bounds__(256) void k_route(const float* __restrict__ logits, const float* __restrict__ gamma,
                                               const float* __restrict__ beta, const float* __restrict__ sumGx,
                                               int* __restrict__ eP, float2* __restrict__ wP,
                                               int* __restrict__ cnts, int* __restrict__ blockHist) {
    __shared__ int h[32];
    int tid = threadIdx.x;
    if (tid < 32) h[tid] = 0;
    __syncthreads();
    float mean = sumGx[0] * (1.0f / 131072.0f);
    float inv_mean = 1.0f / (mean + 1e-6f);
    #pragma unroll
    for (int it = 0; it < 4; it++) {
        size_t t = (size_t)blockIdx.x * 1024 + it * 256 + tid;
        const float4* lr = (const float4*)(logits + t * 16);
        float4 a0 = lr[0], a1 = lr[1], a2 = lr[2], a3 = lr[3];
        float lg[16] = {a0.x, a0.y, a0.z, a0.w, a1.x, a1.y, a1.z, a1.w,
                        a2.x, a2.y, a2.z, a2.w, a3.x, a3.y, a3.z, a3.w};
        float ss = 0.f;
        #pragma unroll
        for (int e = 0; e < 16; e++) ss += lg[e] * lg[e];
        float nx = sqrtf(ss) * inv_mean;
        #pragma unroll
        for (int e = 0; e < 16; e++) lg[e] = gamma[e] * (lg[e] * nx) + beta[e] + lg[e];
        int e1 = 0; float v1 = lg[0];
        #pragma unroll
        for (int e = 1; e < 16; e++) if (lg[e] > v1) { v1 = lg[e]; e1 = e; }
        int e2 = -1; float v2 = -3.4e38f;
        #pragma unroll
        for (int e = 0; e < 16; e++) if (e != e1 && lg[e] > v2) { v2 = lg[e]; e2 = e; }
        float s = 0.f;
        #pragma unroll
        for (int e = 0; e < 16; e++) s += expf(lg[e] - v1);
        float w1 = 1.0f / s;
        float w2 = expf(v2 - v1) / s;
        eP[t] = e1 | (e2 << 8);
        wP[t] = make_float2(w1, w2);
        atomicAdd(&h[e1], 1);
        atomicAdd(&h[16 + e2], 1);
    }
    __syncthreads();
    if (tid < 32) {
        atomicAdd(&cnts[tid], h[tid]);
        blockHist[blockIdx.x * 32 + tid] = h[tid];
    }
}

// ---- scan: per-(block,expert) exclusive bases + per-expert offsets (BM=64 tiles) ----
__global__ void k_scan(int* ctrl, int* blockHist) {
    int t = threadIdx.x;   // 64 threads, one wave
    if (t < 32) {
        int run = 0;
        for (int b = 0; b < 128; b++) {
            int v = blockHist[b * 32 + t];
            blockHist[b * 32 + t] = run;
            run += v;
        }
    }
    __syncthreads();
    if (t == 0) {
        int s = 0;
        for (int e = 0; e < 16; e++) { ctrl[64 + e] = s; s += ctrl[e]; }
        s = 0;
        for (int e = 0; e < 16; e++) { ctrl[80 + e] = s; s += ctrl[16 + e]; }
        int tt = 0; ctrl[96] = 0;
        for (int e = 0; e < 16; e++) { tt += (ctrl[e] + 63) >> 6; ctrl[96 + e + 1] = tt; }
        tt = 0; ctrl[113] = 0;
        for (int e = 0; e < 16; e++) { tt += (ctrl[16 + e] + 63) >> 6; ctrl[113 + e + 1] = tt; }
    }
}

// ---- deterministic token-ordered scatter (ballot ranks, no atomics) ----
__global__ __launch_bounds__(256) void k_scatter(const int* __restrict__ eP, const float2* __restrict__ wP,
                                                 const int* __restrict__ ctrl, const int* __restrict__ blockHist,
                                                 int* __restrict__ listA, float* __restrict__ wA,
                                                 int* __restrict__ listB, float* __restrict__ wB) {
    __shared__ int waveCnt[4][32];
    __shared__ int runCnt[32];
    const int tid = threadIdx.x;
    const int lane = tid & 63;
    const int wv = tid >> 6;
    if (tid < 32) runCnt[tid] = blockHist[blockIdx.x * 32 + tid];
    __syncthreads();
    const unsigned long long below = (1ull << lane) - 1ull;
    for (int it = 0; it < 4; it++) {
        size_t t = (size_t)blockIdx.x * 1024 + it * 256 + tid;
        int ep = eP[t];
        float2 w = wP[t];
        int e1 = ep & 255, e2 = (ep >> 8) & 255;
        int r1 = 0, r2 = 0;
        for (int e = 0; e < 16; e++) {
            unsigned long long m1 = __ballot(e1 == e);
            unsigned long long m2 = __ballot(e2 == e);
            if (e1 == e) r1 = __popcll(m1 & below);
            if (e2 == e) r2 = __popcll(m2 & below);
            if (lane == e) {
                waveCnt[wv][e] = __popcll(m1);
                waveCnt[wv][16 + e] = __popcll(m2);
            }
        }
        __syncthreads();
        if (tid < 32) {
            int s = runCnt[tid];
            #pragma unroll
            for (int ww = 0; ww < 4; ww++) { int v = waveCnt[ww][tid]; waveCnt[ww][tid] = s; s += v; }
            runCnt[tid] = s;
        }
        __syncthreads();
        int i1 = ctrl[64 + e1] + waveCnt[wv][e1] + r1;
        listA[i1] = (int)t; wA[i1] = w.x;
        int i2 = ctrl[80 + e2] + waveCnt[wv][16 + e2] + r2;
        listB[i2] = (int)t; wB[i2] = w.y;
        __syncthreads();
    }
}

// ---- grouped GEMM, BM=64 BN=512(full) BK=64, 8 waves (1Mx8N of 64x64), 72KB LDS ----
// No nh split: A gathered ONCE per pass; epilogue writes full 2KB rows.
// 2 blocks/CU (72KB x2 = 144KB; 128 unified regs/wave x 16 waves) -> 16 waves/CU.
// LDS: B[512][64] @ [0,64K); A[64][64] @ [64K,72K). Epilogue reuses as [16][516] f32.
template <int ADD, int ABF>
__global__ __launch_bounds__(512, 2) void k_gemm(const float* __restrict__ x, const ushort* __restrict__ xbf,
                                                 const ushort* __restrict__ WeT,
                                                 const float* __restrict__ be,
                                                 const int* __restrict__ list, const float* __restrict__ wlist,
                                                 const int* __restrict__ cnts, const int* __restrict__ offs,
                                                 const int* __restrict__ tileOff,
                                                 float* __restrict__ out) {
    __shared__ alignas(16) ushort lds[36864];   // 72 KiB
    const int tid = threadIdx.x;
    // XCD swizzle: gridDim.x divisible by 8 -> bijective chunked remap (m204)
    const int q = (int)gridDim.x >> 3;
    const int ry = ((int)blockIdx.x & 7) * q + ((int)blockIdx.x >> 3);
    if (ry >= tileOff[16]) return;
    int e = 0;
    #pragma unroll
    for (int i = 1; i < 16; i++) if (ry >= tileOff[i]) e = i;
    const int cnt = cnts[e];
    const int off = offs[e];
    const int rowStart = (ry - tileOff[e]) << 6;

    // A staging: 8 threads/row (512 thr -> 64 rows), 8 elems (16B bf16 / 32B f32) each
    const int sRow = tid >> 3, sQ = tid & 7;
    const int gRow = rowStart + sRow;
    const int tokS = (gRow < cnt) ? list[off + gRow] : 0;
    const float* xrowF = x + (size_t)tokS * 512 + sQ * 8;
    const ushort* xrowH = xbf + (size_t)tokS * 512 + sQ * 8;
    const int aswz = (sRow & 7) << 4;
    const int awr0 = 65536 + sRow * 128;

    const char* weB = (const char*)WeT + (size_t)e * 524288;

    const int lane = tid & 63;
    const int wid = tid >> 6;           // 0..7
    const int wN = wid << 6;            // 0..448
    const int l16 = lane & 15;
    const int lq = lane >> 4;
    const int mswz = (l16 & 7) << 4;
    const int kbL = lq << 4;

    f32x4 acc[4][4];
    f32x4 zero = {0.f, 0.f, 0.f, 0.f};
    #pragma unroll
    for (int i = 0; i < 4; i++)
        #pragma unroll
        for (int j = 0; j < 4; j++) acc[i][j] = zero;

    auto stageB = [&](int kt) {         // 64KB: 8 x 16B per thread
        #pragma unroll
        for (int i = 0; i < 8; i++) {
            int D = (tid << 4) + (i << 13);          // 0..65535
            int nr = D >> 7, inner = D & 127;
            int sb = inner ^ ((nr & 7) << 4);
            const char* gp = weB + nr * 1024 + kt * 128 + sb;
            __builtin_amdgcn_global_load_lds((const AS1 void*)gp, (AS3 void*)&lds[D >> 1], 16, 0, 0);
        }
    };
    float4 vaF[2];
    short8 vaH;
    auto loadA = [&](int kt) {
        if (ABF) {
            vaH = *(const short8*)(xrowH + kt * 64);
        } else {
            const float4* xp = (const float4*)(xrowF + kt * 64);
            vaF[0] = xp[0]; vaF[1] = xp[1];
        }
    };
    auto writeA = [&]() {
        int db = awr0 + ((sQ << 4) ^ aswz);
        if (ABF) {
            *(short8*)((char*)lds + db) = vaH;
        } else {
            alignas(16) ushort tw[8];
            float4 p = vaF[0], q2 = vaF[1];
            tw[0] = f2bf(p.x); tw[1] = f2bf(p.y); tw[2] = f2bf(p.z); tw[3] = f2bf(p.w);
            tw[4] = f2bf(q2.x); tw[5] = f2bf(q2.y); tw[6] = f2bf(q2.z); tw[7] = f2bf(q2.w);
            *(short8*)((char*)lds + db) = *(const short8*)tw;
        }
    };
    auto compute = [&]() {
        #pragma unroll
        for (int ks = 0; ks < 2; ks++) {
            const int kb = (ks << 6) + kbL;
            short8 af[4], bfr[4];
            #pragma unroll
            for (int mf = 0; mf < 4; mf++) {
                int m = (mf << 4) + l16;
                af[mf] = *(const short8*)((const char*)lds + 65536 + (m << 7) + (kb ^ mswz));
            }
            #pragma unroll
            for (int nf = 0; nf < 4; nf++) {
                int n = wN + (nf << 4) + l16;
                bfr[nf] = *(const short8*)((const char*)lds + (n << 7) + (kb ^ mswz));
            }
            #pragma unroll
            for (int mf = 0; mf < 4; mf++)
                #pragma unroll
                for (int nf = 0; nf < 4; nf++)
                    acc[mf][nf] = __builtin_amdgcn_mfma_f32_16x16x32_bf16(af[mf], bfr[nf], acc[mf][nf], 0, 0, 0);
        }
    };

    loadA(0);
    #pragma unroll
    for (int kt = 0; kt < 8; kt++) {
        __syncthreads();               // prev compute done -> safe to overwrite LDS
        stageB(kt);
        writeA();
        if (kt < 7) loadA(kt + 1);     // reg-prefetch next A chunk
        __syncthreads();               // stage drained -> safe to read LDS
        compute();
    }

    // ---- coalesced epilogue via LDS transpose (full 512-wide rows) ----
    float bias[4];
    #pragma unroll
    for (int nf = 0; nf < 4; nf++) bias[nf] = be[e * 512 + wN + (nf << 4) + l16];
    float* lsf = (float*)lds;          // 16 rows x 516 f32 = 33 KB (fits 72 KB)
    __syncthreads();
    #pragma unroll
    for (int mf = 0; mf < 4; mf++) {
        int rb = rowStart + (mf << 4) + (lq << 2);
        #pragma unroll
        for (int i = 0; i < 4; i++) {
            int r = rb + i;
            float wv_ = (r < cnt) ? wlist[off + r] : 0.f;
            int lrow = (lq << 2) + i;
            #pragma unroll
            for (int nf = 0; nf < 4; nf++)
                lsf[lrow * 516 + wN + (nf << 4) + l16] = wv_ * (acc[mf][nf][i] + bias[nf]);
        }
        __syncthreads();
        {
            int lrow = tid >> 5, seg = tid & 31;   // 16 rows x 32 segs
            int r = rowStart + (mf << 4) + lrow;
            if (r < cnt) {
                int tok = list[off + r];
                float* orow = out + (size_t)tok * 512;
                #pragma unroll
                for (int j = 0; j < 4; j++) {
                    int c = (seg << 2) + (j << 7);
                    float4 v = *(float4*)&lsf[lrow * 516 + c];
                    if (ADD) {
                        float4 o = *(const float4*)&orow[c];
                        v.x += o.x; v.y += o.y; v.z += o.z; v.w += o.w;
                    }
                    *(float4*)&orow[c] = v;
                }
            }
        }
        __syncthreads();
    }
}

extern "C" void kernel_launch(void* const* d_in, const int* in_sizes, int n_in,
                              void* d_out, int out_size, void* d_ws, size_t ws_size,
                              hipStream_t stream) {
    const float* x = (const float*)d_in[0];
    const float* Wg = (const float*)d_in[1];
    const float* bg = (const float*)d_in[2];
    const float* gamma = (const float*)d_in[3];
    const float* beta = (const float*)d_in[4];
    const float* We = (const float*)d_in[5];
    const float* be = (const float*)d_in[6];
    float* out = (float*)d_out;
    char* ws = (char*)d_ws;

    ushort* WeT = (ushort*)(ws);
    float* logits = (float*)(ws + 8388608);
    int* listA = (int*)(ws + 16777216);
    float* wA = (float*)(ws + 17301504);
    int* listB = (int*)(ws + 17825792);
    float* wB = (float*)(ws + 18350080);
    int* eP = (int*)(ws + 18874368);
    float2* wP = (float2*)(ws + 19398656);
    int* ctrl = (int*)(ws + 20447232);
    int* blockHist = (int*)(ws + 20451328);
    float* ctrlF = (float*)ctrl;
    float* partials = (float*)(ws + 16777216);  // aliases listA; consumed before scatter writes it

    const size_t XBF_OFF = 20480000;
    const size_t XBF_BYTES = (size_t)NTOK * 512 * 2;
    bool useBF = (ws_size >= XBF_OFF + XBF_BYTES);
    ushort* xbf = useBF ? (ushort*)(ws + XBF_OFF) : nullptr;

    // grid: max 64-row tiles = 2048+16 = 2064 (divisible by 8); 512-thread blocks
    k_init<<<1, 256, 0, stream>>>(ctrl);
    k_wet<<<dim3(8, 8, 16), 256, 0, stream>>>(We, WeT);
    k_gate<<<512, 256, 0, stream>>>(x, Wg, bg, logits, partials, xbf);
    k_redsum<<<1, 64, 0, stream>>>(partials, ctrlF + 130);
    k_route<<<128, 256, 0, stream>>>(logits, gamma, beta, ctrlF + 130, eP, wP, ctrl, blockHist);
    k_scan<<<1, 64, 0, stream>>>(ctrl, blockHist);
    k_scatter<<<128, 256, 0, stream>>>(eP, wP, ctrl, blockHist, listA, wA, listB, wB);
    if (useBF) {
        k_gemm<0, 1><<<2064, 512, 0, stream>>>(x, xbf, WeT, be, listA, wA, ctrl, ctrl + 64, ctrl + 96, out);
        k_gemm<1, 1><<<2064, 512, 0, stream>>>(x, xbf, WeT, be, listB, wB, ctrl + 16, ctrl + 80, ctrl + 113, out);
    } else {
        k_gemm<0, 0><<<2064, 512, 0, stream>>>(x, xbf, WeT, be, listA, wA, ctrl, ctrl + 64, ctrl + 96, out);
        k_gemm<1, 0><<<2064, 512, 0, stream>>>(x, xbf, WeT, be, listB, wB, ctrl + 16, ctrl + 80, ctrl + 113, out);
    }
}

// Round 15
// 471.871 us; speedup vs baseline: 1.1096x; 1.1096x over previous
//
#include <hip/hip_runtime.h>
#include <hip/hip_bf16.h>
#include <stdint.h>

#define NTOK 131072
#define NE 16

typedef __attribute__((ext_vector_type(8))) short short8;
typedef __attribute__((ext_vector_type(4))) float f32x4;

#define AS1 __attribute__((address_space(1)))
#define AS3 __attribute__((address_space(3)))

__device__ __forceinline__ ushort f2bf(float f) {
    __hip_bfloat16 h = __float2bfloat16(f);
    return *reinterpret_cast<ushort*>(&h);
}

// ---- ws layout (bytes) ----
// 0        : WeT bf16 [16][512n][512k]          8,388,608
// 8388608  : logits f32 [NTOK][16]              8,388,608
// 16777216 : listA int [NTOK]   (first 2KB doubles as gate partials before scatter)
// 17301504 : wA f32 [NTOK]
// 17825792 : listB int [NTOK]
// 18350080 : wB f32 [NTOK]
// 18874368 : eP int [NTOK]
// 19398656 : wP float2 [NTOK]
// 20447232 : ctrl int[144]
// 20451328 : blockHist int[128][32]             16,384
// 20480000 : xbf bf16 [NTOK][512]              134,217,728   (only if ws_size permits)

__global__ void k_init(int* ctrl) {
    int tid = threadIdx.x;
    if (tid < 144) ctrl[tid] = 0;
}

// ---- transpose+convert We[e][k][n] f32 -> WeT[e][n][k] bf16 ----
__global__ __launch_bounds__(256) void k_wet(const float* __restrict__ We, ushort* __restrict__ WeT) {
    __shared__ float t[64][65];
    int e = blockIdx.z, k0 = blockIdx.x * 64, n0 = blockIdx.y * 64;
    int tid = threadIdx.x;
    const float* src = We + ((size_t)e * 512 + k0) * 512 + n0;
    #pragma unroll
    for (int i = 0; i < 16; i++) {
        int idx = i * 256 + tid;
        int r = idx >> 6, c = idx & 63;
        t[r][c] = src[(size_t)r * 512 + c];
    }
    __syncthreads();
    ushort* dst = WeT + ((size_t)e * 512 + n0) * 512 + k0;
    #pragma unroll
    for (int i = 0; i < 16; i++) {
        int idx = i * 256 + tid;
        int rn = idx >> 6, ck = idx & 63;
        dst[(size_t)rn * 512 + ck] = f2bf(t[ck][rn]);
    }
}

// ---- gating: logits = x@Wg + bg (f32, LDS-staged coalesced); partial of sum||logits||; bf16 x ----
__global__ __launch_bounds__(256) void k_gate(const float* __restrict__ x, const float* __restrict__ Wg,
                                              const float* __restrict__ bg, float* __restrict__ logits,
                                              float* __restrict__ partials, ushort* __restrict__ xbf) {
    __shared__ float WgL[512 * 16];     // 32 KB
    __shared__ float xs[256][33];       // 33.8 KB
    __shared__ float wsum[4];
    const int tid = threadIdx.x;
    #pragma unroll
    for (int i = 0; i < 32; i++) WgL[i * 256 + tid] = Wg[i * 256 + tid];
    const size_t tokBase = (size_t)blockIdx.x * 256;
    float acc[16];
    #pragma unroll
    for (int e = 0; e < 16; e++) acc[e] = 0.f;

    for (int kc = 0; kc < 16; kc++) {
        __syncthreads();
        #pragma unroll
        for (int i = 0; i < 8; i++) {
            int idx = (i << 8) + tid;
            int rr = idx >> 3, cq = (idx & 7) << 2;
            const float4 v = *(const float4*)&x[(tokBase + rr) * 512 + (kc << 5) + cq];
            xs[rr][cq] = v.x; xs[rr][cq + 1] = v.y; xs[rr][cq + 2] = v.z; xs[rr][cq + 3] = v.w;
            if (xbf) {
                ushort4 uw;
                uw.x = f2bf(v.x); uw.y = f2bf(v.y); uw.z = f2bf(v.z); uw.w = f2bf(v.w);
                *(ushort4*)&xbf[(tokBase + rr) * 512 + (kc << 5) + cq] = uw;
            }
        }
        __syncthreads();
        #pragma unroll
        for (int j = 0; j < 32; j++) {
            float xv = xs[tid][j];
            const float* wr = &WgL[((kc << 5) + j) << 4];
            #pragma unroll
            for (int e = 0; e < 16; e++) acc[e] = fmaf(xv, wr[e], acc[e]);
        }
    }

    float lg[16];
    float ss = 0.f;
    #pragma unroll
    for (int e = 0; e < 16; e++) {
        float v = acc[e] + bg[e];
        lg[e] = v;
        ss += v * v;
    }
    float gx = sqrtf(ss);
    float r = gx;
    #pragma unroll
    for (int off = 32; off >= 1; off >>= 1) r += __shfl_down(r, off);
    if ((tid & 63) == 0) wsum[tid >> 6] = r;
    __syncthreads();
    if (tid == 0) partials[blockIdx.x] = wsum[0] + wsum[1] + wsum[2] + wsum[3];
    float4* lo = (float4*)(logits + (tokBase + tid) * 16);
    lo[0] = make_float4(lg[0], lg[1], lg[2], lg[3]);
    lo[1] = make_float4(lg[4], lg[5], lg[6], lg[7]);
    lo[2] = make_float4(lg[8], lg[9], lg[10], lg[11]);
    lo[3] = make_float4(lg[12], lg[13], lg[14], lg[15]);
}

// ---- reduce 512 gate partials -> sumGx ----
__global__ void k_redsum(const float* __restrict__ partials, float* __restrict__ sumGx) {
    int tid = threadIdx.x;  // 64
    float s = 0.f;
    #pragma unroll
    for (int i = 0; i < 8; i++) s += partials[tid + i * 64];
    #pragma unroll
    for (int off = 32; off >= 1; off >>= 1) s += __shfl_down(s, off);
    if (tid == 0) *sumGx = s;
}

// ---- GRN + softmax + top2 + per-expert counts + per-block histograms ----
__global__ __launch_bounds__(256) void k_route(const float* __restrict__ logits, const float* __restrict__ gamma,
                                               const float* __restrict__ beta, const float* __restrict__ sumGx,
                                               int* __restrict__ eP, float2* __restrict__ wP,
                                               int* __restrict__ cnts, int* __restrict__ blockHist) {
    __shared__ int h[32];
    int tid = threadIdx.x;
    if (tid < 32) h[tid] = 0;
    __syncthreads();
    float mean = sumGx[0] * (1.0f / 131072.0f);
    float inv_mean = 1.0f / (mean + 1e-6f);
    #pragma unroll
    for (int it = 0; it < 4; it++) {
        size_t t = (size_t)blockIdx.x * 1024 + it * 256 + tid;
        const float4* lr = (const float4*)(logits + t * 16);
        float4 a0 = lr[0], a1 = lr[1], a2 = lr[2], a3 = lr[3];
        float lg[16] = {a0.x, a0.y, a0.z, a0.w, a1.x, a1.y, a1.z, a1.w,
                        a2.x, a2.y, a2.z, a2.w, a3.x, a3.y, a3.z, a3.w};
        float ss = 0.f;
        #pragma unroll
        for (int e = 0; e < 16; e++) ss += lg[e] * lg[e];
        float nx = sqrtf(ss) * inv_mean;
        #pragma unroll
        for (int e = 0; e < 16; e++) lg[e] = gamma[e] * (lg[e] * nx) + beta[e] + lg[e];
        int e1 = 0; float v1 = lg[0];
        #pragma unroll
        for (int e = 1; e < 16; e++) if (lg[e] > v1) { v1 = lg[e]; e1 = e; }
        int e2 = -1; float v2 = -3.4e38f;
        #pragma unroll
        for (int e = 0; e < 16; e++) if (e != e1 && lg[e] > v2) { v2 = lg[e]; e2 = e; }
        float s = 0.f;
        #pragma unroll
        for (int e = 0; e < 16; e++) s += expf(lg[e] - v1);
        float w1 = 1.0f / s;
        float w2 = expf(v2 - v1) / s;
        eP[t] = e1 | (e2 << 8);
        wP[t] = make_float2(w1, w2);
        atomicAdd(&h[e1], 1);
        atomicAdd(&h[16 + e2], 1);
    }
    __syncthreads();
    if (tid < 32) {
        atomicAdd(&cnts[tid], h[tid]);
        blockHist[blockIdx.x * 32 + tid] = h[tid];
    }
}

// ---- scan: per-(block,expert) exclusive bases + per-expert offsets (BM=128 tiles) ----
__global__ void k_scan(int* ctrl, int* blockHist) {
    int t = threadIdx.x;   // 64 threads, one wave
    if (t < 32) {
        int run = 0;
        for (int b = 0; b < 128; b++) {
            int v = blockHist[b * 32 + t];
            blockHist[b * 32 + t] = run;
            run += v;
        }
    }
    __syncthreads();
    if (t == 0) {
        int s = 0;
        for (int e = 0; e < 16; e++) { ctrl[64 + e] = s; s += ctrl[e]; }
        s = 0;
        for (int e = 0; e < 16; e++) { ctrl[80 + e] = s; s += ctrl[16 + e]; }
        int tt = 0; ctrl[96] = 0;
        for (int e = 0; e < 16; e++) { tt += (ctrl[e] + 127) >> 7; ctrl[96 + e + 1] = tt; }
        tt = 0; ctrl[113] = 0;
        for (int e = 0; e < 16; e++) { tt += (ctrl[16 + e] + 127) >> 7; ctrl[113 + e + 1] = tt; }
    }
}

// ---- deterministic token-ordered scatter (ballot ranks, no atomics) ----
__global__ __launch_bounds__(256) void k_scatter(const int* __restrict__ eP, const float2* __restrict__ wP,
                                                 const int* __restrict__ ctrl, const int* __restrict__ blockHist,
                                                 int* __restrict__ listA, float* __restrict__ wA,
                                                 int* __restrict__ listB, float* __restrict__ wB) {
    __shared__ int waveCnt[4][32];
    __shared__ int runCnt[32];
    const int tid = threadIdx.x;
    const int lane = tid & 63;
    const int wv = tid >> 6;
    if (tid < 32) runCnt[tid] = blockHist[blockIdx.x * 32 + tid];
    __syncthreads();
    const unsigned long long below = (1ull << lane) - 1ull;
    for (int it = 0; it < 4; it++) {
        size_t t = (size_t)blockIdx.x * 1024 + it * 256 + tid;
        int ep = eP[t];
        float2 w = wP[t];
        int e1 = ep & 255, e2 = (ep >> 8) & 255;
        int r1 = 0, r2 = 0;
        for (int e = 0; e < 16; e++) {
            unsigned long long m1 = __ballot(e1 == e);
            unsigned long long m2 = __ballot(e2 == e);
            if (e1 == e) r1 = __popcll(m1 & below);
            if (e2 == e) r2 = __popcll(m2 & below);
            if (lane == e) {
                waveCnt[wv][e] = __popcll(m1);
                waveCnt[wv][16 + e] = __popcll(m2);
            }
        }
        __syncthreads();
        if (tid < 32) {
            int s = runCnt[tid];
            #pragma unroll
            for (int ww = 0; ww < 4; ww++) { int v = waveCnt[ww][tid]; waveCnt[ww][tid] = s; s += v; }
            runCnt[tid] = s;
        }
        __syncthreads();
        int i1 = ctrl[64 + e1] + waveCnt[wv][e1] + r1;
        listA[i1] = (int)t; wA[i1] = w.x;
        int i2 = ctrl[80 + e2] + waveCnt[wv][16 + e2] + r2;
        listB[i2] = (int)t; wB[i2] = w.y;
        __syncthreads();
    }
}

// ---- grouped GEMM, BM=128 BN=256 BK=64, 8 waves (2Mx4N of 64x64), 48KB LDS, 2 blk/CU ----
// 16 waves/CU (the VGPR cap) vs R13's 12; B-staging traffic halves (32KB tile serves
// 128 rows). Per-wave tile stays 64x64 (acc 64 AGPR + 64 VGPR = 128 regs = 4 waves/SIMD).
// LDS: B[256][64] @ [0,32K); A[128][64] @ [32K,48K). Epilogue reuses as [32][260] f32.
template <int ADD, int ABF>
__global__ __launch_bounds__(512, 2) void k_gemm(const float* __restrict__ x, const ushort* __restrict__ xbf,
                                                 const ushort* __restrict__ WeT,
                                                 const float* __restrict__ be,
                                                 const int* __restrict__ list, const float* __restrict__ wlist,
                                                 const int* __restrict__ cnts, const int* __restrict__ offs,
                                                 const int* __restrict__ tileOff,
                                                 float* __restrict__ out) {
    __shared__ alignas(16) ushort lds[24576];   // 48 KiB
    const int tid = threadIdx.x;
    // XCD swizzle: gridDim.x divisible by 8 -> bijective chunked remap (m204)
    const int q = (int)gridDim.x >> 3;
    const int bid = ((int)blockIdx.x & 7) * q + ((int)blockIdx.x >> 3);
    const int ry = bid >> 1;
    const int nh = bid & 1;
    if (ry >= tileOff[16]) return;
    int e = 0;
    #pragma unroll
    for (int i = 1; i < 16; i++) if (ry >= tileOff[i]) e = i;
    const int cnt = cnts[e];
    const int off = offs[e];
    const int rowStart = (ry - tileOff[e]) << 7;   // BM=128
    const int n0 = nh << 8;                        // 0 or 256

    // A staging: 4 threads/row (512 thr -> 128 rows), 16 elems each per K-step
    const int sRow = tid >> 2, sQ = tid & 3;
    const int gRow = rowStart + sRow;
    const int tokS = (gRow < cnt) ? list[off + gRow] : 0;
    const float* xrowF = x + (size_t)tokS * 512 + sQ * 16;
    const ushort* xrowH = xbf + (size_t)tokS * 512 + sQ * 16;
    const int aswz = (sRow & 7) << 4;
    const int awr0 = 32768 + sRow * 128;

    const char* weB = (const char*)WeT + (size_t)e * 524288 + (size_t)n0 * 1024;

    const int lane = tid & 63;
    const int wid = tid >> 6;                 // 0..7
    const int wM = (wid >> 2) << 6;           // 0,64
    const int wN = (wid & 3) << 6;            // 0,64,128,192
    const int l16 = lane & 15;
    const int lq = lane >> 4;
    const int mswz = (l16 & 7) << 4;
    const int kbL = lq << 4;

    f32x4 acc[4][4];
    f32x4 zero = {0.f, 0.f, 0.f, 0.f};
    #pragma unroll
    for (int i = 0; i < 4; i++)
        #pragma unroll
        for (int j = 0; j < 4; j++) acc[i][j] = zero;

    auto stageB = [&](int kt) {               // 32KB: 4 x 16B per thread
        #pragma unroll
        for (int i = 0; i < 4; i++) {
            int D = (tid << 4) + (i << 13);          // 0..32767
            int nr = D >> 7, inner = D & 127;
            int sb = inner ^ ((nr & 7) << 4);
            const char* gp = weB + nr * 1024 + kt * 128 + sb;
            __builtin_amdgcn_global_load_lds((const AS1 void*)gp, (AS3 void*)&lds[D >> 1], 16, 0, 0);
        }
    };
    float4 vaF[4];
    short8 vaH[2];
    auto loadA = [&](int kt) {
        if (ABF) {
            const short8* xp = (const short8*)(xrowH + kt * 64);
            vaH[0] = xp[0]; vaH[1] = xp[1];
        } else {
            const float4* xp = (const float4*)(xrowF + kt * 64);
            #pragma unroll
            for (int j = 0; j < 4; j++) vaF[j] = xp[j];
        }
    };
    auto writeA = [&]() {
        #pragma unroll
        for (int h = 0; h < 2; h++) {
            int db = awr0 + (((sQ << 5) + (h << 4)) ^ aswz);
            if (ABF) {
                *(short8*)((char*)lds + db) = vaH[h];
            } else {
                alignas(16) ushort tw[8];
                float4 p = vaF[h * 2], q2 = vaF[h * 2 + 1];
                tw[0] = f2bf(p.x); tw[1] = f2bf(p.y); tw[2] = f2bf(p.z); tw[3] = f2bf(p.w);
                tw[4] = f2bf(q2.x); tw[5] = f2bf(q2.y); tw[6] = f2bf(q2.z); tw[7] = f2bf(q2.w);
                *(short8*)((char*)lds + db) = *(const short8*)tw;
            }
        }
    };
    auto compute = [&]() {
        #pragma unroll
        for (int ks = 0; ks < 2; ks++) {
            const int kb = (ks << 6) + kbL;
            short8 af[4], bfr[4];
            #pragma unroll
            for (int mf = 0; mf < 4; mf++) {
                int m = wM + (mf << 4) + l16;
                af[mf] = *(const short8*)((const char*)lds + 32768 + (m << 7) + (kb ^ mswz));
            }
            #pragma unroll
            for (int nf = 0; nf < 4; nf++) {
                int n = wN + (nf << 4) + l16;
                bfr[nf] = *(const short8*)((const char*)lds + (n << 7) + (kb ^ mswz));
            }
            #pragma unroll
            for (int mf = 0; mf < 4; mf++)
                #pragma unroll
                for (int nf = 0; nf < 4; nf++)
                    acc[mf][nf] = __builtin_amdgcn_mfma_f32_16x16x32_bf16(af[mf], bfr[nf], acc[mf][nf], 0, 0, 0);
        }
    };

    loadA(0);
    #pragma unroll
    for (int kt = 0; kt < 8; kt++) {
        __syncthreads();               // prev compute done -> safe to overwrite LDS
        stageB(kt);
        writeA();
        if (kt < 7) loadA(kt + 1);     // reg-prefetch next A chunk
        __syncthreads();               // stage drained -> safe to read LDS
        compute();
    }

    // ---- coalesced epilogue via LDS transpose: [32][260] f32 tile per mf ----
    float bias[4];
    #pragma unroll
    for (int nf = 0; nf < 4; nf++) bias[nf] = be[e * 512 + n0 + wN + (nf << 4) + l16];
    float* lsf = (float*)lds;          // 32 rows x 260 f32 = 33.3 KB (fits 48 KB)
    __syncthreads();
    #pragma unroll
    for (int mf = 0; mf < 4; mf++) {
        int rb = rowStart + wM + (mf << 4) + (lq << 2);
        #pragma unroll
        for (int i = 0; i < 4; i++) {
            int r = rb + i;
            float wv_ = (r < cnt) ? wlist[off + r] : 0.f;
            int lrow = ((wid >> 2) << 4) + (lq << 2) + i;   // 0..31
            #pragma unroll
            for (int nf = 0; nf < 4; nf++)
                lsf[lrow * 260 + wN + (nf << 4) + l16] = wv_ * (acc[mf][nf][i] + bias[nf]);
        }
        __syncthreads();
        {
            int lrow = tid >> 4, seg = tid & 15;   // 32 rows x 16 segs
            int r = rowStart + ((lrow >> 4) << 6) + (mf << 4) + (lrow & 15);
            if (r < cnt) {
                int tok = list[off + r];
                float* orow = out + (size_t)tok * 512 + n0;
                #pragma unroll
                for (int j = 0; j < 4; j++) {
                    int c = (seg << 2) + (j << 6);
                    float4 v = *(float4*)&lsf[lrow * 260 + c];
                    if (ADD) {
                        float4 o = *(const float4*)&orow[c];
                        v.x += o.x; v.y += o.y; v.z += o.z; v.w += o.w;
                    }
                    *(float4*)&orow[c] = v;
                }
            }
        }
        __syncthreads();
    }
}

extern "C" void kernel_launch(void* const* d_in, const int* in_sizes, int n_in,
                              void* d_out, int out_size, void* d_ws, size_t ws_size,
                              hipStream_t stream) {
    const float* x = (const float*)d_in[0];
    const float* Wg = (const float*)d_in[1];
    const float* bg = (const float*)d_in[2];
    const float* gamma = (const float*)d_in[3];
    const float* beta = (const float*)d_in[4];
    const float* We = (const float*)d_in[5];
    const float* be = (const float*)d_in[6];
    float* out = (float*)d_out;
    char* ws = (char*)d_ws;

    ushort* WeT = (ushort*)(ws);
    float* logits = (float*)(ws + 8388608);
    int* listA = (int*)(ws + 16777216);
    float* wA = (float*)(ws + 17301504);
    int* listB = (int*)(ws + 17825792);
    float* wB = (float*)(ws + 18350080);
    int* eP = (int*)(ws + 18874368);
    float2* wP = (float2*)(ws + 19398656);
    int* ctrl = (int*)(ws + 20447232);
    int* blockHist = (int*)(ws + 20451328);
    float* ctrlF = (float*)ctrl;
    float* partials = (float*)(ws + 16777216);  // aliases listA; consumed before scatter writes it

    const size_t XBF_OFF = 20480000;
    const size_t XBF_BYTES = (size_t)NTOK * 512 * 2;
    bool useBF = (ws_size >= XBF_OFF + XBF_BYTES);
    ushort* xbf = useBF ? (ushort*)(ws + XBF_OFF) : nullptr;

    // grid: max 128-row tiles = 1024+16 = 1040; x2 nh = 2080 (divisible by 8)
    k_init<<<1, 256, 0, stream>>>(ctrl);
    k_wet<<<dim3(8, 8, 16), 256, 0, stream>>>(We, WeT);
    k_gate<<<512, 256, 0, stream>>>(x, Wg, bg, logits, partials, xbf);
    k_redsum<<<1, 64, 0, stream>>>(partials, ctrlF + 130);
    k_route<<<128, 256, 0, stream>>>(logits, gamma, beta, ctrlF + 130, eP, wP, ctrl, blockHist);
    k_scan<<<1, 64, 0, stream>>>(ctrl, blockHist);
    k_scatter<<<128, 256, 0, stream>>>(eP, wP, ctrl, blockHist, listA, wA, listB, wB);
    if (useBF) {
        k_gemm<0, 1><<<2080, 512, 0, stream>>>(x, xbf, WeT, be, listA, wA, ctrl, ctrl + 64, ctrl + 96, out);
        k_gemm<1, 1><<<2080, 512, 0, stream>>>(x, xbf, WeT, be, listB, wB, ctrl + 16, ctrl + 80, ctrl + 113, out);
    } else {
        k_gemm<0, 0><<<2080, 512, 0, stream>>>(x, xbf, WeT, be, listA, wA, ctrl, ctrl + 64, ctrl + 96, out);
        k_gemm<1, 0><<<2080, 512, 0, stream>>>(x, xbf, WeT, be, listB, wB, ctrl + 16, ctrl + 80, ctrl + 113, out);
    }
}

// Round 17
// 471.494 us; speedup vs baseline: 1.1105x; 1.0008x over previous
//
#include <hip/hip_runtime.h>
#include <hip/hip_bf16.h>
#include <stdint.h>

#define NTOK 131072
#define NE 16

typedef __attribute__((ext_vector_type(8))) short short8;
typedef __attribute__((ext_vector_type(4))) float f32x4;

#define AS1 __attribute__((address_space(1)))
#define AS3 __attribute__((address_space(3)))

__device__ __forceinline__ ushort f2bf(float f) {
    __hip_bfloat16 h = __float2bfloat16(f);
    return *reinterpret_cast<ushort*>(&h);
}

// ---- ws layout (bytes) ----
// 0        : WeT bf16 [16][512n][512k]          8,388,608
// 8388608  : logits f32 [NTOK][16]              8,388,608
// 16777216 : listA int [NTOK]   (first 2KB doubles as gate partials before scatter)
// 17301504 : wA f32 [NTOK]
// 17825792 : listB int [NTOK]
// 18350080 : wB f32 [NTOK]
// 18874368 : eP int [NTOK]
// 19398656 : wP float2 [NTOK]
// 20447232 : ctrl int[144]
// 20451328 : blockHist int[128][32]             16,384
// 20480000 : xbf bf16 [NTOK][512]              134,217,728   (only if ws_size permits)

__global__ void k_init(int* ctrl) {
    int tid = threadIdx.x;
    if (tid < 144) ctrl[tid] = 0;
}

// ---- transpose+convert We[e][k][n] f32 -> WeT[e][n][k] bf16 ----
__global__ __launch_bounds__(256) void k_wet(const float* __restrict__ We, ushort* __restrict__ WeT) {
    __shared__ float t[64][65];
    int e = blockIdx.z, k0 = blockIdx.x * 64, n0 = blockIdx.y * 64;
    int tid = threadIdx.x;
    const float* src = We + ((size_t)e * 512 + k0) * 512 + n0;
    #pragma unroll
    for (int i = 0; i < 16; i++) {
        int idx = i * 256 + tid;
        int r = idx >> 6, c = idx & 63;
        t[r][c] = src[(size_t)r * 512 + c];
    }
    __syncthreads();
    ushort* dst = WeT + ((size_t)e * 512 + n0) * 512 + k0;
    #pragma unroll
    for (int i = 0; i < 16; i++) {
        int idx = i * 256 + tid;
        int rn = idx >> 6, ck = idx & 63;
        dst[(size_t)rn * 512 + ck] = f2bf(t[ck][rn]);
    }
}

// ---- gating: logits = x@Wg + bg (f32, LDS-staged coalesced); partial of sum||logits||; bf16 x ----
__global__ __launch_bounds__(256) void k_gate(const float* __restrict__ x, const float* __restrict__ Wg,
                                              const float* __restrict__ bg, float* __restrict__ logits,
                                              float* __restrict__ partials, ushort* __restrict__ xbf) {
    __shared__ float WgL[512 * 16];     // 32 KB
    __shared__ float xs[256][33];       // 33.8 KB
    __shared__ float wsum[4];
    const int tid = threadIdx.x;
    #pragma unroll
    for (int i = 0; i < 32; i++) WgL[i * 256 + tid] = Wg[i * 256 + tid];
    const size_t tokBase = (size_t)blockIdx.x * 256;
    float acc[16];
    #pragma unroll
    for (int e = 0; e < 16; e++) acc[e] = 0.f;

    for (int kc = 0; kc < 16; kc++) {
        __syncthreads();
        #pragma unroll
        for (int i = 0; i < 8; i++) {
            int idx = (i << 8) + tid;
            int rr = idx >> 3, cq = (idx & 7) << 2;
            const float4 v = *(const float4*)&x[(tokBase + rr) * 512 + (kc << 5) + cq];
            xs[rr][cq] = v.x; xs[rr][cq + 1] = v.y; xs[rr][cq + 2] = v.z; xs[rr][cq + 3] = v.w;
            if (xbf) {
                ushort4 uw;
                uw.x = f2bf(v.x); uw.y = f2bf(v.y); uw.z = f2bf(v.z); uw.w = f2bf(v.w);
                *(ushort4*)&xbf[(tokBase + rr) * 512 + (kc << 5) + cq] = uw;
            }
        }
        __syncthreads();
        #pragma unroll
        for (int j = 0; j < 32; j++) {
            float xv = xs[tid][j];
            const float* wr = &WgL[((kc << 5) + j) << 4];
            #pragma unroll
            for (int e = 0; e < 16; e++) acc[e] = fmaf(xv, wr[e], acc[e]);
        }
    }

    float lg[16];
    float ss = 0.f;
    #pragma unroll
    for (int e = 0; e < 16; e++) {
        float v = acc[e] + bg[e];
        lg[e] = v;
        ss += v * v;
    }
    float gx = sqrtf(ss);
    float r = gx;
    #pragma unroll
    for (int off = 32; off >= 1; off >>= 1) r += __shfl_down(r, off);
    if ((tid & 63) == 0) wsum[tid >> 6] = r;
    __syncthreads();
    if (tid == 0) partials[blockIdx.x] = wsum[0] + wsum[1] + wsum[2] + wsum[3];
    float4* lo = (float4*)(logits + (tokBase + tid) * 16);
    lo[0] = make_float4(lg[0], lg[1], lg[2], lg[3]);
    lo[1] = make_float4(lg[4], lg[5], lg[6], lg[7]);
    lo[2] = make_float4(lg[8], lg[9], lg[10], lg[11]);
    lo[3] = make_float4(lg[12], lg[13], lg[14], lg[15]);
}

// ---- reduce 512 gate partials -> sumGx ----
__global__ void k_redsum(const float* __restrict__ partials, float* __restrict__ sumGx) {
    int tid = threadIdx.x;  // 64
    float s = 0.f;
    #pragma unroll
    for (int i = 0; i < 8; i++) s += partials[tid + i * 64];
    #pragma unroll
    for (int off = 32; off >= 1; off >>= 1) s += __shfl_down(s, off);
    if (tid == 0) *sumGx = s;
}

// ---- GRN + softmax + top2 + per-expert counts + per-block histograms ----
__global__ __launch_bounds__(256) void k_route(const float* __restrict__ logits, const float* __restrict__ gamma,
                                               const float* __restrict__ beta, const float* __restrict__ sumGx,
                                               int* __restrict__ eP, float2* __restrict__ wP,
                                               int* __restrict__ cnts, int* __restrict__ blockHist) {
    __shared__ int h[32];
    int tid = threadIdx.x;
    if (tid < 32) h[tid] = 0;
    __syncthreads();
    float mean = sumGx[0] * (1.0f / 131072.0f);
    float inv_mean = 1.0f / (mean + 1e-6f);
    #pragma unroll
    for (int it = 0; it < 4; it++) {
        size_t t = (size_t)blockIdx.x * 1024 + it * 256 + tid;
        const float4* lr = (const float4*)(logits + t * 16);
        float4 a0 = lr[0], a1 = lr[1], a2 = lr[2], a3 = lr[3];
        float lg[16] = {a0.x, a0.y, a0.z, a0.w, a1.x, a1.y, a1.z, a1.w,
                        a2.x, a2.y, a2.z, a2.w, a3.x, a3.y, a3.z, a3.w};
        float ss = 0.f;
        #pragma unroll
        for (int e = 0; e < 16; e++) ss += lg[e] * lg[e];
        float nx = sqrtf(ss) * inv_mean;
        #pragma unroll
        for (int e = 0; e < 16; e++) lg[e] = gamma[e] * (lg[e] * nx) + beta[e] + lg[e];
        int e1 = 0; float v1 = lg[0];
        #pragma unroll
        for (int e = 1; e < 16; e++) if (lg[e] > v1) { v1 = lg[e]; e1 = e; }
        int e2 = -1; float v2 = -3.4e38f;
        #pragma unroll
        for (int e = 0; e < 16; e++) if (e != e1 && lg[e] > v2) { v2 = lg[e]; e2 = e; }
        float s = 0.f;
        #pragma unroll
        for (int e = 0; e < 16; e++) s += expf(lg[e] - v1);
        float w1 = 1.0f / s;
        float w2 = expf(v2 - v1) / s;
        eP[t] = e1 | (e2 << 8);
        wP[t] = make_float2(w1, w2);
        atomicAdd(&h[e1], 1);
        atomicAdd(&h[16 + e2], 1);
    }
    __syncthreads();
    if (tid < 32) {
        atomicAdd(&cnts[tid], h[tid]);
        blockHist[blockIdx.x * 32 + tid] = h[tid];
    }
}

// ---- scan: per-(block,expert) exclusive bases + per-expert offsets (BM=128 tiles) ----
__global__ void k_scan(int* ctrl, int* blockHist) {
    int t = threadIdx.x;   // 64 threads, one wave
    if (t < 32) {
        int run = 0;
        for (int b = 0; b < 128; b++) {
            int v = blockHist[b * 32 + t];
            blockHist[b * 32 + t] = run;
            run += v;
        }
    }
    __syncthreads();
    if (t == 0) {
        int s = 0;
        for (int e = 0; e < 16; e++) { ctrl[64 + e] = s; s += ctrl[e]; }
        s = 0;
        for (int e = 0; e < 16; e++) { ctrl[80 + e] = s; s += ctrl[16 + e]; }
        int tt = 0; ctrl[96] = 0;
        for (int e = 0; e < 16; e++) { tt += (ctrl[e] + 127) >> 7; ctrl[96 + e + 1] = tt; }
        tt = 0; ctrl[113] = 0;
        for (int e = 0; e < 16; e++) { tt += (ctrl[16 + e] + 127) >> 7; ctrl[113 + e + 1] = tt; }
    }
}

// ---- deterministic token-ordered scatter (ballot ranks, no atomics) ----
__global__ __launch_bounds__(256) void k_scatter(const int* __restrict__ eP, const float2* __restrict__ wP,
                                                 const int* __restrict__ ctrl, const int* __restrict__ blockHist,
                                                 int* __restrict__ listA, float* __restrict__ wA,
                                                 int* __restrict__ listB, float* __restrict__ wB) {
    __shared__ int waveCnt[4][32];
    __shared__ int runCnt[32];
    const int tid = threadIdx.x;
    const int lane = tid & 63;
    const int wv = tid >> 6;
    if (tid < 32) runCnt[tid] = blockHist[blockIdx.x * 32 + tid];
    __syncthreads();
    const unsigned long long below = (1ull << lane) - 1ull;
    for (int it = 0; it < 4; it++) {
        size_t t = (size_t)blockIdx.x * 1024 + it * 256 + tid;
        int ep = eP[t];
        float2 w = wP[t];
        int e1 = ep & 255, e2 = (ep >> 8) & 255;
        int r1 = 0, r2 = 0;
        for (int e = 0; e < 16; e++) {
            unsigned long long m1 = __ballot(e1 == e);
            unsigned long long m2 = __ballot(e2 == e);
            if (e1 == e) r1 = __popcll(m1 & below);
            if (e2 == e) r2 = __popcll(m2 & below);
            if (lane == e) {
                waveCnt[wv][e] = __popcll(m1);
                waveCnt[wv][16 + e] = __popcll(m2);
            }
        }
        __syncthreads();
        if (tid < 32) {
            int s = runCnt[tid];
            #pragma unroll
            for (int ww = 0; ww < 4; ww++) { int v = waveCnt[ww][tid]; waveCnt[ww][tid] = s; s += v; }
            runCnt[tid] = s;
        }
        __syncthreads();
        int i1 = ctrl[64 + e1] + waveCnt[wv][e1] + r1;
        listA[i1] = (int)t; wA[i1] = w.x;
        int i2 = ctrl[80 + e2] + waveCnt[wv][16 + e2] + r2;
        listB[i2] = (int)t; wB[i2] = w.y;
        __syncthreads();
    }
}

// ---- grouped GEMM, BM=128 BN=256 BK=64, 8 waves (2Mx4N of 64x64), 48KB LDS, 2 blk/CU ----
// 16 waves/CU (the VGPR cap) vs R13's 12; B-staging traffic halves (32KB tile serves
// 128 rows). Per-wave tile stays 64x64 (acc 64 AGPR + 64 VGPR = 128 regs = 4 waves/SIMD).
// LDS: B[256][64] @ [0,32K); A[128][64] @ [32K,48K). Epilogue reuses as [32][260] f32.
template <int ADD, int ABF>
__global__ __launch_bounds__(512, 2) void k_gemm(const float* __restrict__ x, const ushort* __restrict__ xbf,
                                                 const ushort* __restrict__ WeT,
                                                 const float* __restrict__ be,
                                                 const int* __restrict__ list, const float* __restrict__ wlist,
                                                 const int* __restrict__ cnts, const int* __restrict__ offs,
                                                 const int* __restrict__ tileOff,
                                                 float* __restrict__ out) {
    __shared__ alignas(16) ushort lds[24576];   // 48 KiB
    const int tid = threadIdx.x;
    // XCD swizzle: gridDim.x divisible by 8 -> bijective chunked remap (m204)
    const int q = (int)gridDim.x >> 3;
    const int bid = ((int)blockIdx.x & 7) * q + ((int)blockIdx.x >> 3);
    const int ry = bid >> 1;
    const int nh = bid & 1;
    if (ry >= tileOff[16]) return;
    int e = 0;
    #pragma unroll
    for (int i = 1; i < 16; i++) if (ry >= tileOff[i]) e = i;
    const int cnt = cnts[e];
    const int off = offs[e];
    const int rowStart = (ry - tileOff[e]) << 7;   // BM=128
    const int n0 = nh << 8;                        // 0 or 256

    // A staging: 4 threads/row (512 thr -> 128 rows), 16 elems each per K-step
    const int sRow = tid >> 2, sQ = tid & 3;
    const int gRow = rowStart + sRow;
    const int tokS = (gRow < cnt) ? list[off + gRow] : 0;
    const float* xrowF = x + (size_t)tokS * 512 + sQ * 16;
    const ushort* xrowH = xbf + (size_t)tokS * 512 + sQ * 16;
    const int aswz = (sRow & 7) << 4;
    const int awr0 = 32768 + sRow * 128;

    const char* weB = (const char*)WeT + (size_t)e * 524288 + (size_t)n0 * 1024;

    const int lane = tid & 63;
    const int wid = tid >> 6;                 // 0..7
    const int wM = (wid >> 2) << 6;           // 0,64
    const int wN = (wid & 3) << 6;            // 0,64,128,192
    const int l16 = lane & 15;
    const int lq = lane >> 4;
    const int mswz = (l16 & 7) << 4;
    const int kbL = lq << 4;

    f32x4 acc[4][4];
    f32x4 zero = {0.f, 0.f, 0.f, 0.f};
    #pragma unroll
    for (int i = 0; i < 4; i++)
        #pragma unroll
        for (int j = 0; j < 4; j++) acc[i][j] = zero;

    auto stageB = [&](int kt) {               // 32KB: 4 x 16B per thread
        #pragma unroll
        for (int i = 0; i < 4; i++) {
            int D = (tid << 4) + (i << 13);          // 0..32767
            int nr = D >> 7, inner = D & 127;
            int sb = inner ^ ((nr & 7) << 4);
            const char* gp = weB + nr * 1024 + kt * 128 + sb;
            __builtin_amdgcn_global_load_lds((const AS1 void*)gp, (AS3 void*)&lds[D >> 1], 16, 0, 0);
        }
    };
    float4 vaF[4];
    short8 vaH[2];
    auto loadA = [&](int kt) {
        if (ABF) {
            const short8* xp = (const short8*)(xrowH + kt * 64);
            vaH[0] = xp[0]; vaH[1] = xp[1];
        } else {
            const float4* xp = (const float4*)(xrowF + kt * 64);
            #pragma unroll
            for (int j = 0; j < 4; j++) vaF[j] = xp[j];
        }
    };
    auto writeA = [&]() {
        #pragma unroll
        for (int h = 0; h < 2; h++) {
            int db = awr0 + (((sQ << 5) + (h << 4)) ^ aswz);
            if (ABF) {
                *(short8*)((char*)lds + db) = vaH[h];
            } else {
                alignas(16) ushort tw[8];
                float4 p = vaF[h * 2], q2 = vaF[h * 2 + 1];
                tw[0] = f2bf(p.x); tw[1] = f2bf(p.y); tw[2] = f2bf(p.z); tw[3] = f2bf(p.w);
                tw[4] = f2bf(q2.x); tw[5] = f2bf(q2.y); tw[6] = f2bf(q2.z); tw[7] = f2bf(q2.w);
                *(short8*)((char*)lds + db) = *(const short8*)tw;
            }
        }
    };
    auto compute = [&]() {
        #pragma unroll
        for (int ks = 0; ks < 2; ks++) {
            const int kb = (ks << 6) + kbL;
            short8 af[4], bfr[4];
            #pragma unroll
            for (int mf = 0; mf < 4; mf++) {
                int m = wM + (mf << 4) + l16;
                af[mf] = *(const short8*)((const char*)lds + 32768 + (m << 7) + (kb ^ mswz));
            }
            #pragma unroll
            for (int nf = 0; nf < 4; nf++) {
                int n = wN + (nf << 4) + l16;
                bfr[nf] = *(const short8*)((const char*)lds + (n << 7) + (kb ^ mswz));
            }
            #pragma unroll
            for (int mf = 0; mf < 4; mf++)
                #pragma unroll
                for (int nf = 0; nf < 4; nf++)
                    acc[mf][nf] = __builtin_amdgcn_mfma_f32_16x16x32_bf16(af[mf], bfr[nf], acc[mf][nf], 0, 0, 0);
        }
    };

    loadA(0);
    #pragma unroll
    for (int kt = 0; kt < 8; kt++) {
        __syncthreads();               // prev compute done -> safe to overwrite LDS
        stageB(kt);
        writeA();
        if (kt < 7) loadA(kt + 1);     // reg-prefetch next A chunk
        __syncthreads();               // stage drained -> safe to read LDS
        compute();
    }

    // ---- coalesced epilogue via LDS transpose: [32][260] f32 tile per mf ----
    float bias[4];
    #pragma unroll
    for (int nf = 0; nf < 4; nf++) bias[nf] = be[e * 512 + n0 + wN + (nf << 4) + l16];
    float* lsf = (float*)lds;          // 32 rows x 260 f32 = 33.3 KB (fits 48 KB)
    __syncthreads();
    #pragma unroll
    for (int mf = 0; mf < 4; mf++) {
        int rb = rowStart + wM + (mf << 4) + (lq << 2);
        #pragma unroll
        for (int i = 0; i < 4; i++) {
            int r = rb + i;
            float wv_ = (r < cnt) ? wlist[off + r] : 0.f;
            int lrow = ((wid >> 2) << 4) + (lq << 2) + i;   // 0..31
            #pragma unroll
            for (int nf = 0; nf < 4; nf++)
                lsf[lrow * 260 + wN + (nf << 4) + l16] = wv_ * (acc[mf][nf][i] + bias[nf]);
        }
        __syncthreads();
        {
            int lrow = tid >> 4, seg = tid & 15;   // 32 rows x 16 segs
            int r = rowStart + ((lrow >> 4) << 6) + (mf << 4) + (lrow & 15);
            if (r < cnt) {
                int tok = list[off + r];
                float* orow = out + (size_t)tok * 512 + n0;
                #pragma unroll
                for (int j = 0; j < 4; j++) {
                    int c = (seg << 2) + (j << 6);
                    float4 v = *(float4*)&lsf[lrow * 260 + c];
                    if (ADD) {
                        float4 o = *(const float4*)&orow[c];
                        v.x += o.x; v.y += o.y; v.z += o.z; v.w += o.w;
                    }
                    *(float4*)&orow[c] = v;
                }
            }
        }
        __syncthreads();
    }
}

extern "C" void kernel_launch(void* const* d_in, const int* in_sizes, int n_in,
                              void* d_out, int out_size, void* d_ws, size_t ws_size,
                              hipStream_t stream) {
    const float* x = (const float*)d_in[0];
    const float* Wg = (const float*)d_in[1];
    const float* bg = (const float*)d_in[2];
    const float* gamma = (const float*)d_in[3];
    const float* beta = (const float*)d_in[4];
    const float* We = (const float*)d_in[5];
    const float* be = (const float*)d_in[6];
    float* out = (float*)d_out;
    char* ws = (char*)d_ws;

    ushort* WeT = (ushort*)(ws);
    float* logits = (float*)(ws + 8388608);
    int* listA = (int*)(ws + 16777216);
    float* wA = (float*)(ws + 17301504);
    int* listB = (int*)(ws + 17825792);
    float* wB = (float*)(ws + 18350080);
    int* eP = (int*)(ws + 18874368);
    float2* wP = (float2*)(ws + 19398656);
    int* ctrl = (int*)(ws + 20447232);
    int* blockHist = (int*)(ws + 20451328);
    float* ctrlF = (float*)ctrl;
    float* partials = (float*)(ws + 16777216);  // aliases listA; consumed before scatter writes it

    const size_t XBF_OFF = 20480000;
    const size_t XBF_BYTES = (size_t)NTOK * 512 * 2;
    bool useBF = (ws_size >= XBF_OFF + XBF_BYTES);
    ushort* xbf = useBF ? (ushort*)(ws + XBF_OFF) : nullptr;

    // grid: max 128-row tiles = 1024+16 = 1040; x2 nh = 2080 (divisible by 8)
    k_init<<<1, 256, 0, stream>>>(ctrl);
    k_wet<<<dim3(8, 8, 16), 256, 0, stream>>>(We, WeT);
    k_gate<<<512, 256, 0, stream>>>(x, Wg, bg, logits, partials, xbf);
    k_redsum<<<1, 64, 0, stream>>>(partials, ctrlF + 130);
    k_route<<<128, 256, 0, stream>>>(logits, gamma, beta, ctrlF + 130, eP, wP, ctrl, blockHist);
    k_scan<<<1, 64, 0, stream>>>(ctrl, blockHist);
    k_scatter<<<128, 256, 0, stream>>>(eP, wP, ctrl, blockHist, listA, wA, listB, wB);
    if (useBF) {
        k_gemm<0, 1><<<2080, 512, 0, stream>>>(x, xbf, WeT, be, listA, wA, ctrl, ctrl + 64, ctrl + 96, out);
        k_gemm<1, 1><<<2080, 512, 0, stream>>>(x, xbf, WeT, be, listB, wB, ctrl + 16, ctrl + 80, ctrl + 113, out);
    } else {
        k_gemm<0, 0><<<2080, 512, 0, stream>>>(x, xbf, WeT, be, listA, wA, ctrl, ctrl + 64, ctrl + 96, out);
        k_gemm<1, 0><<<2080, 512, 0, stream>>>(x, xbf, WeT, be, listB, wB, ctrl + 16, ctrl + 80, ctrl + 113, out);
    }
}